// Round 3
// baseline (422.472 us; speedup 1.0000x reference)
//
#include <hip/hip_runtime.h>
#include <math.h>

// Problem geometry (fixed by setup_inputs)
#define NN 2
#define DD 160
#define HH 192
#define WW 160
#define DO 154   // DD-6
#define HO 186   // HH-6
#define WO 154   // WW-6
// Intermediate: W+H filtered moments, [ch][n][z][ho][wo]
#define CS2 (NN*DD*HO*WO)   // 9,166,080 elements per channel

// K1 tiling: h split into HCH chunks
#define HCH 8
#define HOC 24   // ceil(HO/HCH)

// K2 tiling: z split into ZCH chunks
#define ZCH 8
#define ZOC 20   // ceil(DO/ZCH)

__device__ __forceinline__ unsigned mono_f2u(float f) {
  unsigned u = __float_as_uint(f);
  return (u & 0x80000000u) ? ~u : (u | 0x80000000u);
}

__global__ void init_acc(float* acc) {
  acc[0] = 0.f;  // S_ncc_v
  acc[1] = 0.f;  // S_ncc
  acc[2] = 0.f;  // S_v
  acc[3] = 0.f;  // count
  ((unsigned*)acc)[4] = 0xFFFFFFFFu;  // vmin (monotone-uint; max == +inf)
}

// 7-tap W sums of the 5 moment channels for one input row.
__device__ __forceinline__ void wrow(const float* __restrict__ xp,
                                     const float* __restrict__ yp,
                                     float& t0, float& t1, float& t2,
                                     float& t3, float& t4) {
  t0 = t1 = t2 = t3 = t4 = 0.f;
#pragma unroll
  for (int d = 0; d < 7; ++d) {
    float a = xp[d], b = yp[d];
    t0 += a; t1 += b; t2 += a * a; t3 += b * b; t4 += a * b;
  }
}

// K1: fused W(7-tap direct loads) + H(7-tap sliding add/subtract) filter.
// No ring arrays -> no spill. Old-row recompute loads are L1/L2 hits.
// Thread = (n,z,wo); walks a chunk of h.
__global__ __launch_bounds__(256) void whfilt(const float* __restrict__ X,
                                              const float* __restrict__ Y,
                                              float* __restrict__ B2) {
  const int tx = threadIdx.x & 63;
  const int ty = threadIdx.x >> 6;
  const int wo = blockIdx.x * 64 + tx;
  const int nz = blockIdx.z * 4 + ty;        // n*DD + z, in [0, NN*DD)
  const int h0 = blockIdx.y * HOC;
  const int hout = min(HOC, HO - h0);
  if (wo >= WO) return;

  const float* xr = X + ((size_t)nz * HH + h0) * WW + wo;
  const float* yr = Y + ((size_t)nz * HH + h0) * WW + wo;
  float* out = B2 + ((size_t)nz * HO + h0) * WO + wo;

  float rs0 = 0.f, rs1 = 0.f, rs2 = 0.f, rs3 = 0.f, rs4 = 0.f;
  float t0, t1, t2, t3, t4;
  // prologue: rows h0 .. h0+5
#pragma unroll
  for (int r = 0; r < 6; ++r) {
    wrow(xr + (size_t)r * WW, yr + (size_t)r * WW, t0, t1, t2, t3, t4);
    rs0 += t0; rs1 += t1; rs2 += t2; rs3 += t3; rs4 += t4;
  }
#pragma unroll 2
  for (int o = 0; o < hout; ++o) {
    // add new row o+6
    wrow(xr + (size_t)(o + 6) * WW, yr + (size_t)(o + 6) * WW, t0, t1, t2, t3, t4);
    rs0 += t0; rs1 += t1; rs2 += t2; rs3 += t3; rs4 += t4;
    float* op = out + (size_t)o * WO;
    op[0]       = rs0;
    op[CS2]     = rs1;
    op[2*CS2]   = rs2;
    op[3*CS2]   = rs3;
    op[4*CS2]   = rs4;
    // subtract old row o (cache-hit recompute)
    wrow(xr + (size_t)o * WW, yr + (size_t)o * WW, t0, t1, t2, t3, t4);
    rs0 -= t0; rs1 -= t1; rs2 -= t2; rs3 -= t3; rs4 -= t4;
  }
}

__device__ float block_sum(float v, float* sm) {
  int tid = threadIdx.x;
  sm[tid] = v;
  __syncthreads();
#pragma unroll
  for (int off = 128; off > 0; off >>= 1) {
    if (tid < off) sm[tid] += sm[tid + off];
    __syncthreads();
  }
  float r = sm[0];
  __syncthreads();
  return r;
}

// K2: D 7-tap via sliding add/subtract walking z (5 new + 5 old loads/step,
// old loads are L2/L3 hits), NCC per voxel, block reduction, atomics.
__global__ __launch_bounds__(256) void dncc(const float* __restrict__ B2,
                                            float* __restrict__ acc) {
  const int tx = threadIdx.x & 63;
  const int ty = threadIdx.x >> 6;
  const int wo = blockIdx.x * 64 + tx;
  const int ho = blockIdx.y * 4 + ty;
  const int n  = blockIdx.z >> 3;       // ZCH == 8
  const int ck = blockIdx.z & 7;
  const int z0 = ck * ZOC;
  const int zout = min(ZOC, DO - z0);
  const bool act = (wo < WO) && (ho < HO);

  float p_snv = 0.f, p_sn = 0.f, p_sv = 0.f, p_cnt = 0.f, p_vmin = 3.4e38f;

  if (act) {
    const float* base = B2 + (((size_t)n * DD + z0) * HO + ho) * WO + wo;
    const size_t ZS = (size_t)HO * WO;
    const float inv_nw = 1.0f / 343.0f;
    const float LO = -1.0f - 1e-5f, HI = 1.0f + 1e-5f;

    float rs0 = 0.f, rs1 = 0.f, rs2 = 0.f, rs3 = 0.f, rs4 = 0.f;
#pragma unroll
    for (int i = 0; i < 6; ++i) {
      const float* p = base + (size_t)i * ZS;
      rs0 += p[0]; rs1 += p[CS2]; rs2 += p[2*CS2]; rs3 += p[3*CS2]; rs4 += p[4*CS2];
    }
#pragma unroll 2
    for (int o = 0; o < zout; ++o) {
      const float* pn = base + (size_t)(o + 6) * ZS;
      const float* po = base + (size_t)o * ZS;
      float n0 = pn[0], n1 = pn[CS2], n2 = pn[2*CS2], n3 = pn[3*CS2], n4 = pn[4*CS2];
      float o0 = po[0], o1 = po[CS2], o2 = po[2*CS2], o3 = po[3*CS2], o4 = po[4*CS2];
      rs0 += n0; rs1 += n1; rs2 += n2; rs3 += n3; rs4 += n4;

      float num = rs4 - rs0 * rs1 * inv_nw;
      float d0  = rs2 - rs0 * rs0 * inv_nw;
      float d1  = rs3 - rs1 * rs1 * inv_nw;
      float den = d0 * d1;
      if (den > 1e-5f) {
        float ncc = num / sqrtf(den);
        if (ncc >= LO && ncc <= HI) {
          float v = 0.5f * (d0 + d1);
          p_snv += ncc * v;
          p_sn  += ncc;
          p_sv  += v;
          p_cnt += 1.f;
          p_vmin = fminf(p_vmin, v);
        }
      }
      rs0 -= o0; rs1 -= o1; rs2 -= o2; rs3 -= o3; rs4 -= o4;
    }
  }

  __shared__ float sm[256];
  float bsnv = block_sum(p_snv, sm);
  float bsn  = block_sum(p_sn, sm);
  float bsv  = block_sum(p_sv, sm);
  float bcnt = block_sum(p_cnt, sm);
  int tid = threadIdx.x;
  sm[tid] = p_vmin;
  __syncthreads();
#pragma unroll
  for (int off = 128; off > 0; off >>= 1) {
    if (tid < off) sm[tid] = fminf(sm[tid], sm[tid + off]);
    __syncthreads();
  }
  if (tid == 0) {
    atomicAdd(&acc[0], bsnv);
    atomicAdd(&acc[1], bsn);
    atomicAdd(&acc[2], bsv);
    atomicAdd(&acc[3], bcnt);
    atomicMin((unsigned*)acc + 4, mono_f2u(sm[0]));
  }
}

// loss = 1 - (S_nv - vmin*S_n) / (S_v - vmin*cnt); min-max scale cancels.
__global__ void fin(const float* __restrict__ acc, float* __restrict__ out) {
  float snv = acc[0], sn = acc[1], sv = acc[2], cnt = acc[3];
  unsigned u = ((const unsigned*)acc)[4];
  unsigned bits = (u & 0x80000000u) ? (u ^ 0x80000000u) : ~u;
  float vmin = __uint_as_float(bits);
  out[0] = 1.0f - (snv - vmin * sn) / (sv - vmin * cnt);
}

extern "C" void kernel_launch(void* const* d_in, const int* in_sizes, int n_in,
                              void* d_out, int out_size, void* d_ws, size_t ws_size,
                              hipStream_t stream) {
  const float* X = (const float*)d_in[0];  // y_pred
  const float* Y = (const float*)d_in[1];  // y_true
  // d_in[2]: ones kernel, constant, unused.

  float* acc = (float*)d_ws;
  float* B2  = (float*)((char*)d_ws + 256);

  init_acc<<<1, 1, 0, stream>>>(acc);
  // K1: grid = (wo tiles, h chunks, n*z / 4)
  dim3 g1((WO + 63) / 64, HCH, NN * DD / 4);
  whfilt<<<g1, 256, 0, stream>>>(X, Y, B2);
  // K2: grid = (wo tiles, ho tiles, n * z-chunks)
  dim3 g2((WO + 63) / 64, (HO + 3) / 4, NN * ZCH);
  dncc<<<g2, 256, 0, stream>>>(B2, acc);
  fin<<<1, 1, 0, stream>>>(acc, (float*)d_out);
}

// Round 4
// 293.430 us; speedup vs baseline: 1.4398x; 1.4398x over previous
//
#include <hip/hip_runtime.h>
#include <math.h>

// Problem geometry (fixed by setup_inputs)
#define NN 2
#define DD 160
#define HH 192
#define WW 160
#define DO 154   // DD-6
#define HO 186   // HH-6
#define WO 154   // WW-6

// Tiling: block = 256 threads = 64 (wo) x 4 (ho), walks a z-chunk.
#define WOT 64
#define HOT 4
#define NWO 3    // ceil(WO/64)
#define NHO 47   // ceil(HO/4)
#define ZCH 4
#define ZOC 39   // ceil(DO/4)
#define NB (NWO * NHO * NN * ZCH)   // 1128 blocks

__device__ __forceinline__ float block_sum(float v, float* sm) {
  int tid = threadIdx.x;
  sm[tid] = v;
  __syncthreads();
#pragma unroll
  for (int off = 128; off > 0; off >>= 1) {
    if (tid < off) sm[tid] += sm[tid + off];
    __syncthreads();
  }
  float r = sm[0];
  __syncthreads();
  return r;
}

__device__ __forceinline__ float block_min(float v, float* sm) {
  int tid = threadIdx.x;
  sm[tid] = v;
  __syncthreads();
#pragma unroll
  for (int off = 128; off > 0; off >>= 1) {
    if (tid < off) sm[tid] = fminf(sm[tid], sm[tid + off]);
    __syncthreads();
  }
  float r = sm[0];
  __syncthreads();
  return r;
}

// Fully fused: W-filter (cooperative, LDS R) + H-filter (7 LDS reads) +
// z-window (7-slot LDS ring + register running sums) + NCC + block reduce.
// No intermediate in HBM: total global traffic = X+Y reads (L3-resident).
__global__ __launch_bounds__(256) void ncc_fused(const float* __restrict__ X,
                                                 const float* __restrict__ Y,
                                                 float* __restrict__ part) {
  __shared__ float R[5][HOT + 6][WOT];        // 12.8 KB  W-filtered moment rows
  __shared__ float ring[7][5][HOT][WOT];      // 35.84 KB z-window history
  __shared__ float sm[256];

  const int tid = threadIdx.x;
  const int tx = tid & 63;
  const int ty = tid >> 6;
  const int wo0 = blockIdx.x * WOT;
  const int ho0 = blockIdx.y * HOT;
  const int n   = blockIdx.z >> 2;            // ZCH == 4
  const int ck  = blockIdx.z & 3;
  const int z0  = ck * ZOC;
  const int zout = min(ZOC, DO - z0);
  const int nslice = zout + 6;

  // zero the ring (read-before-first-write slots must be 0)
  {
    float* r0 = &ring[0][0][0][0];
    for (int i = tid; i < 7 * 5 * HOT * WOT; i += 256) r0[i] = 0.f;
  }

  const int wo = wo0 + tx;
  const int ho = ho0 + ty;
  const bool act = (wo < WO) && (ho < HO);

  float zs0 = 0.f, zs1 = 0.f, zs2 = 0.f, zs3 = 0.f, zs4 = 0.f;
  float p_snv = 0.f, p_sn = 0.f, p_sv = 0.f, p_cnt = 0.f, p_vmin = 3.4e38f;

  const size_t slice = (size_t)HH * WW;
  const float* Xn = X + (size_t)n * DD * slice;
  const float* Yn = Y + (size_t)n * DD * slice;
  const float inv_nw = 1.0f / 343.0f;
  const float LO = -1.0f - 1e-5f, HI = 1.0f + 1e-5f;

  int slot = 0;
  for (int s = 0; s < nslice; ++s) {
    const int zi = z0 + s;
    __syncthreads();  // previous iteration's R readers are done
    // ---- Phase A: W-filtered moment rows for this z-slice ----
    for (int i = tid; i < (HOT + 6) * WOT; i += 256) {
      const int r = i >> 6;     // input row offset 0..9
      const int c = i & 63;     // output col offset
      const int h = ho0 + r;
      float t0 = 0.f, t1 = 0.f, t2 = 0.f, t3 = 0.f, t4 = 0.f;
      if (h < HH && (wo0 + c) < WO) {
        const float* xp = Xn + (size_t)zi * slice + (size_t)h * WW + (wo0 + c);
        const float* yp = Yn + (size_t)zi * slice + (size_t)h * WW + (wo0 + c);
#pragma unroll
        for (int d = 0; d < 7; ++d) {
          float a = xp[d], b = yp[d];
          t0 += a; t1 += b; t2 += a * a; t3 += b * b; t4 += a * b;
        }
      }
      R[0][r][c] = t0; R[1][r][c] = t1; R[2][r][c] = t2;
      R[3][r][c] = t3; R[4][r][c] = t4;
    }
    __syncthreads();
    // ---- Phase B: H-filter + z-window update + NCC ----
    float m0 = 0.f, m1 = 0.f, m2 = 0.f, m3 = 0.f, m4 = 0.f;
#pragma unroll
    for (int j = 0; j < 7; ++j) {
      m0 += R[0][ty + j][tx];
      m1 += R[1][ty + j][tx];
      m2 += R[2][ty + j][tx];
      m3 += R[3][ty + j][tx];
      m4 += R[4][ty + j][tx];
    }
    zs0 += m0 - ring[slot][0][ty][tx]; ring[slot][0][ty][tx] = m0;
    zs1 += m1 - ring[slot][1][ty][tx]; ring[slot][1][ty][tx] = m1;
    zs2 += m2 - ring[slot][2][ty][tx]; ring[slot][2][ty][tx] = m2;
    zs3 += m3 - ring[slot][3][ty][tx]; ring[slot][3][ty][tx] = m3;
    zs4 += m4 - ring[slot][4][ty][tx]; ring[slot][4][ty][tx] = m4;
    slot = (slot == 6) ? 0 : slot + 1;

    if (s >= 6 && act) {
      float num = zs4 - zs0 * zs1 * inv_nw;
      float d0  = zs2 - zs0 * zs0 * inv_nw;
      float d1  = zs3 - zs1 * zs1 * inv_nw;
      float den = d0 * d1;
      if (den > 1e-5f) {
        float ncc = num / sqrtf(den);
        if (ncc >= LO && ncc <= HI) {
          float v = 0.5f * (d0 + d1);
          p_snv += ncc * v;
          p_sn  += ncc;
          p_sv  += v;
          p_cnt += 1.f;
          p_vmin = fminf(p_vmin, v);
        }
      }
    }
  }

  // ---- block reduce, write partials ----
  float bsnv = block_sum(p_snv, sm);
  float bsn  = block_sum(p_sn, sm);
  float bsv  = block_sum(p_sv, sm);
  float bcnt = block_sum(p_cnt, sm);
  float bmin = block_min(p_vmin, sm);
  if (tid == 0) {
    const int bid = blockIdx.x + NWO * (blockIdx.y + NHO * blockIdx.z);
    float* pp = part + (size_t)bid * 8;
    pp[0] = bsnv; pp[1] = bsn; pp[2] = bsv; pp[3] = bcnt; pp[4] = bmin;
  }
}

// Reduce NB per-block partials; loss = 1 - (S_nv - vmin*S_n)/(S_v - vmin*cnt)
// (the min-max weight scale HIGH/(vmax-vmin+1e-12) cancels in w/sum(w)).
__global__ __launch_bounds__(256) void fin(const float* __restrict__ part,
                                           float* __restrict__ out) {
  __shared__ float sm[256];
  const int tid = threadIdx.x;
  float s0 = 0.f, s1 = 0.f, s2 = 0.f, s3 = 0.f, vm = 3.4e38f;
  for (int b = tid; b < NB; b += 256) {
    const float* pp = part + (size_t)b * 8;
    s0 += pp[0]; s1 += pp[1]; s2 += pp[2]; s3 += pp[3];
    vm = fminf(vm, pp[4]);
  }
  s0 = block_sum(s0, sm);
  s1 = block_sum(s1, sm);
  s2 = block_sum(s2, sm);
  s3 = block_sum(s3, sm);
  vm = block_min(vm, sm);
  if (tid == 0) {
    out[0] = 1.0f - (s0 - vm * s1) / (s2 - vm * s3);
  }
}

extern "C" void kernel_launch(void* const* d_in, const int* in_sizes, int n_in,
                              void* d_out, int out_size, void* d_ws, size_t ws_size,
                              hipStream_t stream) {
  const float* X = (const float*)d_in[0];  // y_pred
  const float* Y = (const float*)d_in[1];  // y_true
  // d_in[2]: ones kernel, constant, unused.

  float* part = (float*)d_ws;  // NB * 8 floats = 36 KB

  dim3 g(NWO, NHO, NN * ZCH);
  ncc_fused<<<g, 256, 0, stream>>>(X, Y, part);
  fin<<<1, 256, 0, stream>>>(part, (float*)d_out);
}

// Round 5
// 273.496 us; speedup vs baseline: 1.5447x; 1.0729x over previous
//
#include <hip/hip_runtime.h>
#include <math.h>

// Problem geometry (fixed by setup_inputs)
#define NN 2
#define DD 160
#define HH 192
#define WW 160
#define DO 154   // DD-6
#define HO 186   // HH-6
#define WO 154   // WW-6

// Tiling: block = 256 threads = 64 (wo) x 4 (ho), walks a z-chunk.
#define WOT 64
#define HOT 4
#define NWO 3    // ceil(WO/64)
#define NHO 47   // ceil(HO/4)
#define ZCH 4
#define ZOC 39   // ceil(DO/4)
#define NB (NWO * NHO * NN * ZCH)   // 1128 blocks

__device__ __forceinline__ float block_sum(float v, float* sm) {
  int tid = threadIdx.x;
  sm[tid] = v;
  __syncthreads();
#pragma unroll
  for (int off = 128; off > 0; off >>= 1) {
    if (tid < off) sm[tid] += sm[tid + off];
    __syncthreads();
  }
  float r = sm[0];
  __syncthreads();
  return r;
}

__device__ __forceinline__ float block_min(float v, float* sm) {
  int tid = threadIdx.x;
  sm[tid] = v;
  __syncthreads();
#pragma unroll
  for (int off = 128; off > 0; off >>= 1) {
    if (tid < off) sm[tid] = fminf(sm[tid], sm[tid + off]);
    __syncthreads();
  }
  float r = sm[0];
  __syncthreads();
  return r;
}

// Fully fused NCC. Per z-slice: Phase A computes W-filtered moment rows into
// a double-buffered LDS tile (pair-vectorized: 2 outputs from 8 inputs via
// float2 loads); Phase B H-sums 7 rows, maintains the 7-deep z-window in a
// REGISTER shift-chain (constant indices; launch_bounds caps occupancy so the
// compiler doesn't spill it), computes NCC, accumulates block partials.
// One __syncthreads per slice; Phase-A loads for s+1 overlap Phase B of s.
__global__ __launch_bounds__(256, 4) void ncc_fused(const float* __restrict__ X,
                                                    const float* __restrict__ Y,
                                                    float* __restrict__ part) {
  __shared__ float R[2][5][HOT + 6][WOT];   // 25.6 KB, double-buffered
  __shared__ float sm[256];

  const int tid = threadIdx.x;
  const int tx = tid & 63;
  const int ty = tid >> 6;
  const int wo0 = blockIdx.x * WOT;
  const int ho0 = blockIdx.y * HOT;
  const int n   = blockIdx.z >> 2;            // ZCH == 4
  const int ck  = blockIdx.z & 3;
  const int z0  = ck * ZOC;
  const int zout = min(ZOC, DO - z0);
  const int nslice = zout + 6;

  const int wo = wo0 + tx;
  const int ho = ho0 + ty;
  const bool act = (wo < WO) && (ho < HO);

  const size_t slice = (size_t)HH * WW;
  const float* Xn = X + (size_t)n * DD * slice;
  const float* Yn = Y + (size_t)n * DD * slice;
  const float inv_nw = 1.0f / 343.0f;
  const float LO = -1.0f - 1e-5f, HI = 1.0f + 1e-5f;

  // Phase A: W-filtered moments for input slice z0+s_in into R[buf].
  // 320 pair-items; item p -> row r=p>>5 (0..9), cols cp,cp+1 (cp even).
  auto phaseA = [&](int s_in, int buf) {
    const int zi = z0 + s_in;
    const float* Xs = Xn + (size_t)zi * slice;
    const float* Ys = Yn + (size_t)zi * slice;
#pragma unroll
    for (int k = 0; k < 2; ++k) {
      const int p = tid + k * 256;
      if (p < 320) {
        const int r  = p >> 5;
        const int cp = (p & 31) << 1;
        const int h  = ho0 + r;
        float a0 = 0.f, a1 = 0.f, a2 = 0.f, a3 = 0.f, a4 = 0.f;
        float b0 = 0.f, b1 = 0.f, b2 = 0.f, b3 = 0.f, b4 = 0.f;
        if ((h < HH) && (wo0 + cp < WO)) {
          const float2* xp = (const float2*)(Xs + (size_t)h * WW + wo0 + cp);
          const float2* yp = (const float2*)(Ys + (size_t)h * WW + wo0 + cp);
          float2 xa = xp[0], xb = xp[1], xc = xp[2], xd = xp[3];
          float2 ya = yp[0], yb = yp[1], yc = yp[2], yd = yp[3];
          float x[8] = {xa.x, xa.y, xb.x, xb.y, xc.x, xc.y, xd.x, xd.y};
          float y[8] = {ya.x, ya.y, yb.x, yb.y, yc.x, yc.y, yd.x, yd.y};
#pragma unroll
          for (int i = 0; i < 7; ++i) {
            a0 += x[i]; a1 += y[i];
            a2 += x[i] * x[i]; a3 += y[i] * y[i]; a4 += x[i] * y[i];
          }
          b0 = a0 - x[0] + x[7];
          b1 = a1 - y[0] + y[7];
          b2 = a2 - x[0] * x[0] + x[7] * x[7];
          b3 = a3 - y[0] * y[0] + y[7] * y[7];
          b4 = a4 - x[0] * y[0] + x[7] * y[7];
        }
        R[buf][0][r][cp] = a0; R[buf][0][r][cp + 1] = b0;
        R[buf][1][r][cp] = a1; R[buf][1][r][cp + 1] = b1;
        R[buf][2][r][cp] = a2; R[buf][2][r][cp + 1] = b2;
        R[buf][3][r][cp] = a3; R[buf][3][r][cp + 1] = b3;
        R[buf][4][r][cp] = a4; R[buf][4][r][cp + 1] = b4;
      }
    }
  };

  // z-window register state: shift-chain q[ch][0..6], q[...][6] == m(s-7)
  float q0[7], q1[7], q2[7], q3[7], q4[7];
#pragma unroll
  for (int i = 0; i < 7; ++i) { q0[i] = 0.f; q1[i] = 0.f; q2[i] = 0.f; q3[i] = 0.f; q4[i] = 0.f; }
  float zs0 = 0.f, zs1 = 0.f, zs2 = 0.f, zs3 = 0.f, zs4 = 0.f;
  float p_snv = 0.f, p_sn = 0.f, p_sv = 0.f, p_cnt = 0.f, p_vmin = 3.4e38f;

  phaseA(0, 0);
  __syncthreads();

  for (int s = 0; s < nslice; ++s) {
    const int cb = s & 1;
    // Phase A for next slice into the other buffer (loads overlap Phase B)
    if (s + 1 < nslice) phaseA(s + 1, 1 - cb);

    // Phase B: H 7-tap from R[cb]
    float m0 = 0.f, m1 = 0.f, m2 = 0.f, m3 = 0.f, m4 = 0.f;
#pragma unroll
    for (int j = 0; j < 7; ++j) {
      m0 += R[cb][0][ty + j][tx];
      m1 += R[cb][1][ty + j][tx];
      m2 += R[cb][2][ty + j][tx];
      m3 += R[cb][3][ty + j][tx];
      m4 += R[cb][4][ty + j][tx];
    }
    // z-window update (register shift-chain)
    zs0 += m0 - q0[6]; zs1 += m1 - q1[6]; zs2 += m2 - q2[6];
    zs3 += m3 - q3[6]; zs4 += m4 - q4[6];
#pragma unroll
    for (int i = 6; i > 0; --i) {
      q0[i] = q0[i - 1]; q1[i] = q1[i - 1]; q2[i] = q2[i - 1];
      q3[i] = q3[i - 1]; q4[i] = q4[i - 1];
    }
    q0[0] = m0; q1[0] = m1; q2[0] = m2; q3[0] = m3; q4[0] = m4;

    if (s >= 6 && act) {
      float num = zs4 - zs0 * zs1 * inv_nw;
      float d0  = zs2 - zs0 * zs0 * inv_nw;
      float d1  = zs3 - zs1 * zs1 * inv_nw;
      float den = d0 * d1;
      if (den > 1e-5f) {
        float ncc = num / sqrtf(den);
        if (ncc >= LO && ncc <= HI) {
          float v = 0.5f * (d0 + d1);
          p_snv += ncc * v;
          p_sn  += ncc;
          p_sv  += v;
          p_cnt += 1.f;
          p_vmin = fminf(p_vmin, v);
        }
      }
    }
    __syncthreads();   // R[1-cb] writes complete; R[cb] readers done
  }

  // ---- block reduce, write partials ----
  float bsnv = block_sum(p_snv, sm);
  float bsn  = block_sum(p_sn, sm);
  float bsv  = block_sum(p_sv, sm);
  float bcnt = block_sum(p_cnt, sm);
  float bmin = block_min(p_vmin, sm);
  if (tid == 0) {
    const int bid = blockIdx.x + NWO * (blockIdx.y + NHO * blockIdx.z);
    float* pp = part + (size_t)bid * 8;
    pp[0] = bsnv; pp[1] = bsn; pp[2] = bsv; pp[3] = bcnt; pp[4] = bmin;
  }
}

// Reduce NB per-block partials; loss = 1 - (S_nv - vmin*S_n)/(S_v - vmin*cnt)
// (the min-max weight scale HIGH/(vmax-vmin+1e-12) cancels in w/sum(w)).
__global__ __launch_bounds__(256) void fin(const float* __restrict__ part,
                                           float* __restrict__ out) {
  __shared__ float sm[256];
  const int tid = threadIdx.x;
  float s0 = 0.f, s1 = 0.f, s2 = 0.f, s3 = 0.f, vm = 3.4e38f;
  for (int b = tid; b < NB; b += 256) {
    const float* pp = part + (size_t)b * 8;
    s0 += pp[0]; s1 += pp[1]; s2 += pp[2]; s3 += pp[3];
    vm = fminf(vm, pp[4]);
  }
  s0 = block_sum(s0, sm);
  s1 = block_sum(s1, sm);
  s2 = block_sum(s2, sm);
  s3 = block_sum(s3, sm);
  vm = block_min(vm, sm);
  if (tid == 0) {
    out[0] = 1.0f - (s0 - vm * s1) / (s2 - vm * s3);
  }
}

extern "C" void kernel_launch(void* const* d_in, const int* in_sizes, int n_in,
                              void* d_out, int out_size, void* d_ws, size_t ws_size,
                              hipStream_t stream) {
  const float* X = (const float*)d_in[0];  // y_pred
  const float* Y = (const float*)d_in[1];  // y_true
  // d_in[2]: ones kernel, constant, unused.

  float* part = (float*)d_ws;  // NB * 8 floats = 36 KB

  dim3 g(NWO, NHO, NN * ZCH);
  ncc_fused<<<g, 256, 0, stream>>>(X, Y, part);
  fin<<<1, 256, 0, stream>>>(part, (float*)d_out);
}

// Round 7
// 177.520 us; speedup vs baseline: 2.3799x; 1.5406x over previous
//
#include <hip/hip_runtime.h>
#include <math.h>

// Problem geometry (fixed by setup_inputs)
#define NN 2
#define DD 160
#define HH 192
#define WW 160
#define DO 154   // DD-6
#define HO 186   // HH-6
#define WO 154   // WW-6

#define NWO 3    // wo tiles of 64
#define NHO 47   // ho tiles of 4
#define ZCH 8    // z chunks
#define ZOC 20   // ceil(DO/ZCH)
#define NB (NWO * NHO * NN * ZCH)   // 2256 blocks

// LDS-only barrier: s_waitcnt lgkmcnt(0) (vmcnt left outstanding) + s_barrier.
// Global prefetch loads stay in flight across the barrier (CK block_sync_lds).
#define LDS_SYNC() do { __builtin_amdgcn_s_waitcnt(0xC07F); __builtin_amdgcn_s_barrier(); } while (0)

__device__ __forceinline__ float block_sum(float v, float* sm) {
  int tid = threadIdx.x;
  sm[tid] = v;
  __syncthreads();
#pragma unroll
  for (int off = 128; off > 0; off >>= 1) {
    if (tid < off) sm[tid] += sm[tid + off];
    __syncthreads();
  }
  float r = sm[0];
  __syncthreads();
  return r;
}

__device__ __forceinline__ float block_min(float v, float* sm) {
  int tid = threadIdx.x;
  sm[tid] = v;
  __syncthreads();
#pragma unroll
  for (int off = 128; off > 0; off >>= 1) {
    if (tid < off) sm[tid] = fminf(sm[tid], sm[tid + off]);
    __syncthreads();
  }
  float r = sm[0];
  __syncthreads();
  return r;
}

__global__ __launch_bounds__(256, 4) void ncc_fused(const float* __restrict__ X,
                                                    const float* __restrict__ Y,
                                                    float* __restrict__ part) {
  __shared__ __align__(16) float R[5][10][64];   // 12.8 KB W-filtered moment rows
  __shared__ __align__(16) float Mh[5][4][64];   // 5 KB   W+H-filtered moments
  __shared__ float sm[256];

  const int tid = threadIdx.x;
  const int tx = tid & 63, ty = tid >> 6;
  const int wo0 = blockIdx.x * 64;
  const int ho0 = blockIdx.y * 4;
  const int n   = blockIdx.z >> 3;   // ZCH == 8
  const int ck  = blockIdx.z & 7;
  const int z0  = ck * ZOC;
  const int zout = min(ZOC, DO - z0);
  const int nslice = zout + 6;

  const int wo = wo0 + tx, ho = ho0 + ty;
  const bool act = (wo < WO) && (ho < HO);

  const size_t slice = (size_t)HH * WW;
  const float* Xn = X + (size_t)n * DD * slice;
  const float* Yn = Y + (size_t)n * DD * slice;
  const float inv_nw = 1.0f / 343.0f;
  const float LO = -1.0f - 1e-5f, HI = 1.0f + 1e-5f;

  // Phase-A quad item: 160 items, item p -> row r=p>>4 (0..9), cols cq..cq+3.
  const int pA  = tid;
  const bool hasA = (pA < 160);
  const int rA  = pA >> 4;
  const int cqA = (pA & 15) << 2;
  const int hA  = ho0 + rA;
  const int baseW = wo0 + cqA;                 // even multiple of 4, <=152 when valid
  const bool okA  = hasA && (hA < HH) && (baseW < WO);
  const bool tail = okA && (baseW + 9 >= WW);  // last float2 would cross the row
  const float* XrowA = Xn + (size_t)hA * WW + baseW;
  const float* YrowA = Yn + (size_t)hA * WW + baseW;

  float4 lx0 = {0,0,0,0}, lx1 = {0,0,0,0}, ly0 = {0,0,0,0}, ly1 = {0,0,0,0};
  float2 lx2 = {0,0}, ly2 = {0,0};

  auto loadA = [&](int s_in) {
    if (okA) {
      const float* xp = XrowA + (size_t)(z0 + s_in) * slice;
      const float* yp = YrowA + (size_t)(z0 + s_in) * slice;
      lx0 = *(const float4*)xp; lx1 = *(const float4*)(xp + 4);
      ly0 = *(const float4*)yp; ly1 = *(const float4*)(yp + 4);
      if (!tail) { lx2 = *(const float2*)(xp + 8); ly2 = *(const float2*)(yp + 8); }
      else       { lx2 = make_float2(0.f, 0.f);    ly2 = make_float2(0.f, 0.f); }
    }
  };

  auto storeA = [&]() {
    if (okA) {
      float x0=lx0.x,x1=lx0.y,x2=lx0.z,x3=lx0.w,x4=lx1.x,x5=lx1.y,x6=lx1.z,x7=lx1.w,x8=lx2.x,x9=lx2.y;
      float y0=ly0.x,y1=ly0.y,y2=ly0.z,y3=ly0.w,y4=ly1.x,y5=ly1.y,y6=ly1.z,y7=ly1.w,y8=ly2.x,y9=ly2.y;
      {
        float a = x0+x1+x2+x3+x4+x5+x6;
        float b = a - x0 + x7, c = b - x1 + x8, d = c - x2 + x9;
        *(float4*)&R[0][rA][cqA] = make_float4(a, b, c, d);
      }
      {
        float a = y0+y1+y2+y3+y4+y5+y6;
        float b = a - y0 + y7, c = b - y1 + y8, d = c - y2 + y9;
        *(float4*)&R[1][rA][cqA] = make_float4(a, b, c, d);
      }
      {
        float a = x0*x0+x1*x1+x2*x2+x3*x3+x4*x4+x5*x5+x6*x6;
        float b = a - x0*x0 + x7*x7, c = b - x1*x1 + x8*x8, d = c - x2*x2 + x9*x9;
        *(float4*)&R[2][rA][cqA] = make_float4(a, b, c, d);
      }
      {
        float a = y0*y0+y1*y1+y2*y2+y3*y3+y4*y4+y5*y5+y6*y6;
        float b = a - y0*y0 + y7*y7, c = b - y1*y1 + y8*y8, d = c - y2*y2 + y9*y9;
        *(float4*)&R[3][rA][cqA] = make_float4(a, b, c, d);
      }
      {
        float a = x0*y0+x1*y1+x2*y2+x3*y3+x4*y4+x5*y5+x6*y6;
        float b = a - x0*y0 + x7*y7, c = b - x1*y1 + x8*y8, d = c - x2*y2 + x9*y9;
        *(float4*)&R[4][rA][cqA] = make_float4(a, b, c, d);
      }
    }
  };

  // Phase H: incremental 7-tap H-sums (10 reads -> 4 outputs per (ch,wo)).
  auto phaseH = [&]() {
    {
      const int ch = ty, w = tx;   // items 0..255
      const float* rp = &R[ch][0][w];
      float r0=rp[0],r1=rp[64],r2=rp[128],r3=rp[192],r4=rp[256],
            r5=rp[320],r6=rp[384],r7=rp[448],r8=rp[512],r9=rp[576];
      float m0 = r0+r1+r2+r3+r4+r5+r6;
      float m1 = m0 - r0 + r7, m2 = m1 - r1 + r8, m3 = m2 - r2 + r9;
      Mh[ch][0][w]=m0; Mh[ch][1][w]=m1; Mh[ch][2][w]=m2; Mh[ch][3][w]=m3;
    }
    if (tx < 16) {                 // items 256..319 (ch=4), 16 per wave
      const int w = ty * 16 + tx;
      const float* rp = &R[4][0][w];
      float r0=rp[0],r1=rp[64],r2=rp[128],r3=rp[192],r4=rp[256],
            r5=rp[320],r6=rp[384],r7=rp[448],r8=rp[512],r9=rp[576];
      float m0 = r0+r1+r2+r3+r4+r5+r6;
      float m1 = m0 - r0 + r7, m2 = m1 - r1 + r8, m3 = m2 - r2 + r9;
      Mh[4][0][w]=m0; Mh[4][1][w]=m1; Mh[4][2][w]=m2; Mh[4][3][w]=m3;
    }
  };

  // Rotating 7-phase accumulators (no ring storage, no shift movs).
  float a0[7], a1[7], a2[7], a3[7], a4[7];
#pragma unroll
  for (int j = 0; j < 7; ++j) { a0[j]=0.f; a1[j]=0.f; a2[j]=0.f; a3[j]=0.f; a4[j]=0.f; }
  float p_snv = 0.f, p_sn = 0.f, p_sv = 0.f, p_cnt = 0.f, p_vmin = 3.4e38f;

  loadA(0);
  storeA();
  __syncthreads();

  for (int sb = 0; sb < nslice; sb += 7) {
#pragma unroll
    for (int u = 0; u < 7; ++u) {
      const int s = sb + u;
      if (s < nslice) {                       // wave-uniform
        if (s + 1 < nslice) loadA(s + 1);     // global -> regs (stays in flight)
        phaseH();                             // R -> Mh
        LDS_SYNC();
        {                                      // Phase O: Mh -> accumulators
          float m0 = Mh[0][ty][tx], m1 = Mh[1][ty][tx], m2 = Mh[2][ty][tx],
                m3 = Mh[3][ty][tx], m4 = Mh[4][ty][tx];
#pragma unroll
          for (int j = 0; j < 7; ++j) {
            a0[j]+=m0; a1[j]+=m1; a2[j]+=m2; a3[j]+=m3; a4[j]+=m4;
          }
          if (s >= 6 && act) {
            float zs0=a0[u], zs1=a1[u], zs2=a2[u], zs3=a3[u], zs4=a4[u];
            float num = zs4 - zs0 * zs1 * inv_nw;
            float d0  = zs2 - zs0 * zs0 * inv_nw;
            float d1  = zs3 - zs1 * zs1 * inv_nw;
            float den = d0 * d1;
            if (den > 1e-5f) {
              float ncc = num * __frsqrt_rn(den);
              if (ncc >= LO && ncc <= HI) {
                float v = 0.5f * (d0 + d1);
                p_snv += ncc * v; p_sn += ncc; p_sv += v; p_cnt += 1.f;
                p_vmin = fminf(p_vmin, v);
              }
            }
          }
          a0[u]=0.f; a1[u]=0.f; a2[u]=0.f; a3[u]=0.f; a4[u]=0.f;
        }
        if (s + 1 < nslice) storeA();         // vmcnt wait lands HERE
        LDS_SYNC();
      }
    }
  }

  float bsnv = block_sum(p_snv, sm);
  float bsn  = block_sum(p_sn, sm);
  float bsv  = block_sum(p_sv, sm);
  float bcnt = block_sum(p_cnt, sm);
  float bmin = block_min(p_vmin, sm);
  if (tid == 0) {
    const int bid = blockIdx.x + NWO * (blockIdx.y + NHO * blockIdx.z);
    float* pp = part + (size_t)bid * 8;
    pp[0] = bsnv; pp[1] = bsn; pp[2] = bsv; pp[3] = bcnt; pp[4] = bmin;
  }
}

// loss = 1 - (S_nv - vmin*S_n)/(S_v - vmin*cnt); min-max weight scale cancels.
__global__ __launch_bounds__(256) void fin(const float* __restrict__ part,
                                           float* __restrict__ out) {
  __shared__ float sm[256];
  const int tid = threadIdx.x;
  float s0 = 0.f, s1 = 0.f, s2 = 0.f, s3 = 0.f, vm = 3.4e38f;
  for (int b = tid; b < NB; b += 256) {
    const float* pp = part + (size_t)b * 8;
    s0 += pp[0]; s1 += pp[1]; s2 += pp[2]; s3 += pp[3];
    vm = fminf(vm, pp[4]);
  }
  s0 = block_sum(s0, sm);
  s1 = block_sum(s1, sm);
  s2 = block_sum(s2, sm);
  s3 = block_sum(s3, sm);
  vm = block_min(vm, sm);
  if (tid == 0) {
    out[0] = 1.0f - (s0 - vm * s1) / (s2 - vm * s3);
  }
}

extern "C" void kernel_launch(void* const* d_in, const int* in_sizes, int n_in,
                              void* d_out, int out_size, void* d_ws, size_t ws_size,
                              hipStream_t stream) {
  const float* X = (const float*)d_in[0];  // y_pred
  const float* Y = (const float*)d_in[1];  // y_true
  // d_in[2]: ones kernel, constant, unused.

  float* part = (float*)d_ws;  // NB * 8 floats = 72 KB

  dim3 g(NWO, NHO, NN * ZCH);
  ncc_fused<<<g, 256, 0, stream>>>(X, Y, part);
  fin<<<1, 256, 0, stream>>>(part, (float*)d_out);
}